// Round 8
// baseline (5125.562 us; speedup 1.0000x reference)
//
#include <hip/hip_runtime.h>
#include <hip/hip_fp16.h>

// LSTM B=8192 S=1024 H=256 — round 8: r7 phase structure, 4-wave blocks =>
// TWO INDEPENDENT blocks per CU (one wave of each per SIMD).
// r7 post-mortem: 2 waves/SIMD of the SAME block stall at the same barrier;
// VALUBusy capped at 54%. Fix: block = 256 thr (4 waves) owning 32 rows x
// 64 j (j-quarter); per-thread work identical to r7 (16 j/wave, wfrag 128
// regs STATIC-indexed, 8 cells/thread) -> reg class 256, launch_bounds(256,2)
// -> 2 independent blocks/CU whose stalls interleave.
// Quads {b0,b0+8,+16,+24} (same XCD both dispatch maps) share 64 rows =
// 2 staggered sets of 32. Per phase: acc-init(x,w0,bias) -> K-loop (16 ds_read
// + 64 MFMA) -> poll 3 peer flags + 16KB DMA for other set (lands a phase
// early) -> elementwise -> publish own 4KB quarter from regs -> ONE barrier.

typedef _Float16 f16x8 __attribute__((ext_vector_type(8)));
typedef float f32x4 __attribute__((ext_vector_type(4)));
typedef unsigned int u32;
typedef unsigned short u16;

#define WINT_OFF 0u
#define W0B_OFF  524288u
#define FLAG_OFF 528384u   // int[512 blocks][2 sets][16] = 64 KB
#define PUB_OFF  1048576u  // u16[(set*2+par)][128 quad][4 quarter][2048] = 8 MB

static __device__ __forceinline__ float fast_exp2(float x) {
#if __has_builtin(__builtin_amdgcn_exp2f)
  return __builtin_amdgcn_exp2f(x);
#else
  return exp2f(x);
#endif
}
static __device__ __forceinline__ float fast_rcp(float x) {
#if __has_builtin(__builtin_amdgcn_rcpf)
  return __builtin_amdgcn_rcpf(x);
#else
  return 1.0f / x;
#endif
}
static __device__ __forceinline__ float fsig(float x) {
  return fast_rcp(1.0f + fast_exp2(-1.44269504f * x));
}
static __device__ __forceinline__ float ftanh_(float x) {
  float e = fast_exp2(2.88539008f * x);
  return 1.0f - 2.0f * fast_rcp(e + 1.0f);
}
static __device__ __forceinline__ u16 f16b(float f) {
  union { _Float16 h; u16 u; } cv; cv.h = (_Float16)f; return cv.u;
}
static __device__ __forceinline__ float h2f(u16 u) {
  union { u16 u; _Float16 h; } cv; cv.u = u; return (float)cv.h;
}
// 16 KB quad image for (set, parity, quad): 4 quarter images of [32 b][64 j].
static __device__ __forceinline__ u16* pub_base(u16* pub, int set, int par, int qd) {
  return pub + ((size_t)((set * 2 + par) * 128 + qd) << 13);
}

// Wint[n][k], n = g*256 + j (plain); w0b[n] = packed fp16 {w0, bias}.
__global__ void lstm_prep(const float* __restrict__ Wf, const float* __restrict__ Wi,
                          const float* __restrict__ Wc, const float* __restrict__ Wo,
                          const float* __restrict__ bf_, const float* __restrict__ bi_,
                          const float* __restrict__ bc_, const float* __restrict__ bo_,
                          u16* __restrict__ Wint, u32* __restrict__ w0b) {
  int n = blockIdx.x;       // 0..1023
  int k = threadIdx.x;      // 0..255
  int g = n >> 8, j = n & 255;
  const float* Ws = (g == 0) ? Wf : (g == 1) ? Wi : (g == 2) ? Wc : Wo;
  Wint[n * 256 + k] = f16b(Ws[j * 257 + 1 + k]);
  if (k == 0) {
    const float* bs = (g == 0) ? bf_ : (g == 1) ? bi_ : (g == 2) ? bc_ : bo_;
    w0b[n] = (u32)f16b(Ws[j * 257]) | ((u32)f16b(bs[j]) << 16);
  }
}

// Zero parity-0 pub of both sets (h_0 = 0), flags (64 KB), out = bout.
__global__ void lstm_zero(uint4* __restrict__ pub4, uint4* __restrict__ flags4,
                          float* __restrict__ out, const float* __restrict__ bout) {
  int idx = blockIdx.x * 256 + threadIdx.x;
  uint4 z = uint4{0, 0, 0, 0};
  if (idx < 131072) pub4[idx] = z;                 // slot (s0,p0): 2 MB
  else if (idx < 262144) pub4[idx + 131072] = z;   // slot (s1,p0): 2 MB
  else if (idx < 266240) flags4[idx - 262144] = z; // 64 KB flags
  else { int o = idx - 266240; if (o < 8192) out[o] = bout[0]; }
}

__global__ __launch_bounds__(256, 2) void lstm_main(
    const u16* __restrict__ Wint, const u32* __restrict__ w0b,
    const float* __restrict__ x, const float* __restrict__ Wout,
    float* __restrict__ out, u16* __restrict__ pub, int* __restrict__ flags) {

  __shared__ __align__(16) u16 stg[2][4][2048];  // [set][quarter][32 b x 64 j]

  const int tid  = threadIdx.x;
  const int wv   = tid >> 6;       // 0..3
  const int lane = tid & 63;
  const int l15  = lane & 15;
  const int quad = lane >> 4;
  const int B    = blockIdx.x;                  // 0..511
  const int qi   = (B >> 3) & 3;                // quarter index in quad
  const int qd   = (B & 7) | ((B >> 5) << 3);   // quad 0..127
  const int b0   = (qd & 7) | ((qd >> 3) << 5); // member-0 block id
  const int rows0 = qd * 64;
  const int j0g  = qi * 64 + wv * 16;           // this wave's global j base

  // ---- one-time: W A-fragments (128 regs, STATIC reg indices; qi/wv only in
  // addresses). wfrag[g][ks]: rows n = g*256 + j0g + l15, k = ks*32 + quad*8.
  f16x8 wfrag[4][8];
#pragma unroll
  for (int g = 0; g < 4; ++g)
#pragma unroll
    for (int ks = 0; ks < 8; ++ks)
      wfrag[g][ks] = *(const f16x8*)(Wint +
          (size_t)(g * 256 + j0g + l15) * 256 + ks * 32 + quad * 8);
  uint4 w0bv[4];
#pragma unroll
  for (int g = 0; g < 4; ++g)
    w0bv[g] = *(const uint4*)(w0b + g * 256 + j0g + quad * 4);

  // zero stg (h_0 images = 0): 32 KB = 2048 uint4, 256 threads
#pragma unroll
  for (int i = 0; i < 8; ++i) ((uint4*)stg)[tid + i * 256] = uint4{0, 0, 0, 0};

  float cst[2][2][4];   // [set][bt][r]: cell (b = bt*16+l15, j = j0g+quad*4+r)
#pragma unroll
  for (int s = 0; s < 2; ++s)
#pragma unroll
    for (int bt = 0; bt < 2; ++bt)
#pragma unroll
      for (int r = 0; r < 4; ++r) cst[s][bt][r] = 0.0f;

  const float* xq = x + (size_t)rows0 * 1024;
  float xcur[2][2];
#pragma unroll
  for (int s = 0; s < 2; ++s)
#pragma unroll
    for (int bt = 0; bt < 2; ++bt)
      xcur[s][bt] = xq[(size_t)(s * 32 + bt * 16 + l15) * 1024];

  int* const myflag = flags + B * 32;
  int* pfl[3];
#pragma unroll
  for (int d = 0; d < 3; ++d)
    pfl[d] = flags + (b0 + (((qi + d + 1) & 3) << 3)) * 32;

  __syncthreads();

#pragma unroll 1
  for (int t = 0; t < 1024; ++t) {
#pragma unroll
    for (int s = 0; s < 2; ++s) {
      // 1. acc init = x*w0 + bias
      f32x4 acc[4][2];
#pragma unroll
      for (int g = 0; g < 4; ++g) {
        u32 pka[4] = {w0bv[g].x, w0bv[g].y, w0bv[g].z, w0bv[g].w};
#pragma unroll
        for (int r = 0; r < 4; ++r) {
          float w0f = h2f((u16)pka[r]), bsf = h2f((u16)(pka[r] >> 16));
          acc[g][0][r] = xcur[s][0] * w0f + bsf;
          acc[g][1][r] = xcur[s][1] * w0f + bsf;
        }
      }
      // x prefetch for (s, t+1) — drained by phase-end barrier
#pragma unroll
      for (int bt = 0; bt < 2; ++bt)
        xcur[s][bt] = xq[(size_t)(s * 32 + bt * 16 + l15) * 1024 + ((t + 1) & 1023)];

      // 2. K-loop over full 256 k (quarter-major stg; DMA'd last phase)
#pragma unroll
      for (int ks = 0; ks < 8; ++ks) {
        const u16* qimg = &stg[s][ks >> 1][0];
        f16x8 bb[2];
#pragma unroll
        for (int bt = 0; bt < 2; ++bt) {
          int b = bt * 16 + l15;
          int c = (((ks & 1) * 4 + quad)) ^ (b & 7);
          bb[bt] = *(const f16x8*)(qimg + b * 64 + c * 8);
        }
#pragma unroll
        for (int g = 0; g < 4; ++g)
#pragma unroll
          for (int bt = 0; bt < 2; ++bt)
            acc[g][bt] = __builtin_amdgcn_mfma_f32_16x16x32_f16(
                wfrag[g][ks], bb[bt], acc[g][bt], 0, 0, 0);
      }

      // 3. poll 3 peer flags + DMA full 16 KB quad image for the OTHER set
      const int tn = (s == 0) ? t : t + 1;
      if (tn < 1024) {
#pragma unroll
        for (int d = 0; d < 3; ++d)
          while (__hip_atomic_load(pfl[d] + (s ^ 1) * 16, __ATOMIC_RELAXED,
                                   __HIP_MEMORY_SCOPE_AGENT) < tn)
            __builtin_amdgcn_s_sleep(1);
        const u16* src = pub_base(pub, s ^ 1, tn & 1, qd);
#pragma unroll
        for (int i = 0; i < 4; ++i) {
          int ch = (i * 4 + wv) * 64;   // wave-uniform chunk base
          __builtin_amdgcn_global_load_lds(
              (const __attribute__((address_space(1))) u32*)(src + (ch + lane) * 8),
              (__attribute__((address_space(3))) u32*)(&stg[s ^ 1][0][0] + ch * 8),
              16, 0, 0);
        }
      }

      // 4. elementwise + publish own quarter straight from regs
      u16* pb = pub_base(pub, s, (t + 1) & 1, qd) + qi * 2048;
#pragma unroll
      for (int bt = 0; bt < 2; ++bt) {
        int b = bt * 16 + l15;
        u32 lo, hi;
        {
          float h0, h1, h2, h3;
#pragma unroll
          for (int r = 0; r < 4; ++r) {
            float fg = acc[0][bt][r], ig = acc[1][bt][r];
            float cg = acc[2][bt][r], og = acc[3][bt][r];
            float c_ = fsig(fg) * cst[s][bt][r] + fsig(ig) * ftanh_(cg);
            cst[s][bt][r] = c_;
            float hv = fsig(og) * ftanh_(c_);
            if (r == 0) h0 = hv; else if (r == 1) h1 = hv;
            else if (r == 2) h2 = hv; else h3 = hv;
          }
          lo = (u32)f16b(h0) | ((u32)f16b(h1) << 16);
          hi = (u32)f16b(h2) | ((u32)f16b(h3) << 16);
        }
        int jc = wv * 2 + (quad >> 1);           // j-chunk (8 j) within quarter
        int c  = jc ^ (b & 7);                   // swizzled chunk position
        *(uint2*)(pb + b * 64 + c * 8 + (quad & 1) * 4) = uint2{lo, hi};
      }

      // 5. single barrier: implicit vmcnt(0) drains publish + DMA + x loads
      __syncthreads();
      if (tid == 0)
        __hip_atomic_store(myflag + s * 16, t + 1, __ATOMIC_RELAXED,
                           __HIP_MEMORY_SCOPE_AGENT);
    }
  }

  // ---- out[b] += (own 64-j quarter of h_1024) . Wout  (out pre-set to bout) ----
  if (tid < 64) {
    int s = tid >> 5, b = tid & 31;
    const u16* pbase = pub_base(pub, s, 0, qd) + qi * 2048;  // parity of t=1024 is 0
    float a = 0.0f;
#pragma unroll
    for (int c = 0; c < 8; ++c) {
      f16x8 hv = *(const f16x8*)(pbase + b * 64 + ((c ^ (b & 7)) * 8));
#pragma unroll
      for (int e = 0; e < 8; ++e) a += (float)hv[e] * Wout[qi * 64 + c * 8 + e];
    }
    atomicAdd(&out[rows0 + s * 32 + b], a);
  }
}

extern "C" void kernel_launch(void* const* d_in, const int* in_sizes, int n_in,
                              void* d_out, int out_size, void* d_ws, size_t ws_size,
                              hipStream_t stream) {
  const float* x    = (const float*)d_in[0];
  const float* Wf   = (const float*)d_in[1];
  const float* bf_  = (const float*)d_in[2];
  const float* Wi   = (const float*)d_in[3];
  const float* bi_  = (const float*)d_in[4];
  const float* Wc   = (const float*)d_in[5];
  const float* bc_  = (const float*)d_in[6];
  const float* Wo   = (const float*)d_in[7];
  const float* bo_  = (const float*)d_in[8];
  const float* Wout = (const float*)d_in[9];
  const float* bout = (const float*)d_in[10];

  u16* Wint  = (u16*)((char*)d_ws + WINT_OFF);
  u32* w0b   = (u32*)((char*)d_ws + W0B_OFF);
  int* flags = (int*)((char*)d_ws + FLAG_OFF);
  u16* pub   = (u16*)((char*)d_ws + PUB_OFF);

  lstm_prep<<<1024, 256, 0, stream>>>(Wf, Wi, Wc, Wo, bf_, bi_, bc_, bo_, Wint, w0b);
  lstm_zero<<<1072, 256, 0, stream>>>((uint4*)pub, (uint4*)flags, (float*)d_out, bout);
  lstm_main<<<512, 256, 0, stream>>>(Wint, w0b, x, Wout, (float*)d_out, pub, flags);
}